// Round 2
// baseline (718.425 us; speedup 1.0000x reference)
//
#include <hip/hip_runtime.h>

// DeepGCN: 3-layer GCN, N=50000 nodes, E=800000 edges, 512->128->64->2.
// Strategy: build CSR (by dst) on device each call; transform-then-aggregate;
// fuse bias+BN+ReLU into aggregation epilogue; fuse GEMM3 into agg2 via
// wave reduce. All fp32 this round.

constexpr int NN = 50000;
constexpr int NE = 800000;
constexpr float BN_EPS = 1e-5f;

// ---------------- CSR build ----------------

__global__ void k_count(const int* __restrict__ dst, int* __restrict__ cnt, int e) {
    int i = blockIdx.x * 256 + threadIdx.x;
    if (i < e) atomicAdd(&cnt[dst[i]], 1);
}

__global__ void k_dis(const int* __restrict__ cnt, float* __restrict__ dis, int n) {
    int i = blockIdx.x * 256 + threadIdx.x;
    if (i < n) dis[i] = rsqrtf((float)(cnt[i] + 1));   // +1 = self loop
}

__global__ __launch_bounds__(1024) void k_scan(const int* __restrict__ cnt,
                                               int* __restrict__ row_start, int n) {
    __shared__ int tmp[1024];
    int tid = threadIdx.x;
    int running = 0;
    if (tid == 0) row_start[0] = 0;
    for (int base = 0; base < n; base += 1024) {
        int v = (base + tid < n) ? cnt[base + tid] : 0;
        tmp[tid] = v;
        __syncthreads();
        for (int off = 1; off < 1024; off <<= 1) {
            int t = (tid >= off) ? tmp[tid - off] : 0;
            __syncthreads();
            tmp[tid] += t;
            __syncthreads();
        }
        if (base + tid < n) row_start[base + tid + 1] = running + tmp[tid];
        running += tmp[1023];
        __syncthreads();   // protect tmp before next iteration's overwrite
    }
}

__global__ void k_fill(const int* __restrict__ src, const int* __restrict__ dst,
                       const int* __restrict__ row_start, int* __restrict__ cursor,
                       int* __restrict__ csr, int e) {
    int i = blockIdx.x * 256 + threadIdx.x;
    if (i < e) {
        int d = dst[i];
        int pos = atomicAdd(&cursor[d], 1);
        csr[row_start[d] + pos] = src[i];
    }
}

// ---------------- tiled fp32 GEMM: C[M,Nn] = A[M,K] @ B[K,Nn] ----------------

template <int BM, int BN, int BK, int TM, int TN>
__global__ __launch_bounds__((BM / TM) * (BN / TN))
void gemm_f32(const float* __restrict__ A, const float* __restrict__ B,
              float* __restrict__ C, int M, int K, int Nn) {
    constexpr int TX = BN / TN;
    constexpr int TY = BM / TM;
    constexpr int NT = TX * TY;
    __shared__ float As[BK][BM + 4];
    __shared__ float Bs[BK][BN];
    const int bm = blockIdx.x * BM;
    const int bn = blockIdx.y * BN;
    const int tid = threadIdx.x;
    const int tx = tid % TX, ty = tid / TX;

    float acc[TM][TN] = {};

    for (int k0 = 0; k0 < K; k0 += BK) {
        // A tile: BM x BK (row-major source), store transposed As[k][m]
        #pragma unroll
        for (int i = tid; i < BM * BK / 4; i += NT) {
            int row = i / (BK / 4);
            int kk = (i % (BK / 4)) * 4;
            float4 v = make_float4(0.f, 0.f, 0.f, 0.f);
            if (bm + row < M)
                v = *reinterpret_cast<const float4*>(&A[(size_t)(bm + row) * K + k0 + kk]);
            As[kk + 0][row] = v.x;
            As[kk + 1][row] = v.y;
            As[kk + 2][row] = v.z;
            As[kk + 3][row] = v.w;
        }
        // B tile: BK x BN
        #pragma unroll
        for (int i = tid; i < BK * BN / 4; i += NT) {
            int kk = i / (BN / 4);
            int col = (i % (BN / 4)) * 4;
            *reinterpret_cast<float4*>(&Bs[kk][col]) =
                *reinterpret_cast<const float4*>(&B[(size_t)(k0 + kk) * Nn + bn + col]);
        }
        __syncthreads();

        #pragma unroll
        for (int kk = 0; kk < BK; ++kk) {
            float a[TM], b[TN];
            #pragma unroll
            for (int m = 0; m < TM; ++m) a[m] = As[kk][ty * TM + m];
            #pragma unroll
            for (int n2 = 0; n2 < TN; ++n2) b[n2] = Bs[kk][tx * TN + n2];
            #pragma unroll
            for (int m = 0; m < TM; ++m)
                #pragma unroll
                for (int n2 = 0; n2 < TN; ++n2) acc[m][n2] += a[m] * b[n2];
        }
        __syncthreads();
    }

    #pragma unroll
    for (int m = 0; m < TM; ++m) {
        int row = bm + ty * TM + m;
        if (row < M) {
            #pragma unroll
            for (int n2 = 0; n2 < TN; n2 += 4) {
                float4 v = {acc[m][n2], acc[m][n2 + 1], acc[m][n2 + 2], acc[m][n2 + 3]};
                *reinterpret_cast<float4*>(&C[(size_t)row * Nn + bn + tx * TN + n2]) = v;
            }
        }
    }
}

// ---------------- aggregation kernels ----------------
// out[i] = dis[i]^2 * h[i] + sum_{e:(s->i)} dis[s]*dis[i]*h[s], then epilogue.

// F=128: one wave per node, 2 channels per lane (float2). Fused bias+BN+ReLU.
__global__ __launch_bounds__(256)
void agg1_bnrelu(const float* __restrict__ h, const float* __restrict__ dis,
                 const int* __restrict__ row_start, const int* __restrict__ csr,
                 const float* __restrict__ b, const float* __restrict__ g,
                 const float* __restrict__ beta, const float* __restrict__ mean,
                 const float* __restrict__ var, float* __restrict__ out, int n) {
    int node = (blockIdx.x * 256 + threadIdx.x) >> 6;
    int lane = threadIdx.x & 63;
    if (node >= n) return;
    float di = dis[node];
    const float2* hp = reinterpret_cast<const float2*>(h);
    float2 hv = hp[(size_t)node * 64 + lane];
    float accx = hv.x * di * di;
    float accy = hv.y * di * di;
    int rs = row_start[node], re = row_start[node + 1];
    for (int j = rs; j < re; ++j) {
        int s = csr[j];
        float w = dis[s] * di;
        float2 v = hp[(size_t)s * 64 + lane];
        accx += v.x * w;
        accy += v.y * w;
    }
    int f0 = lane * 2;
    float s0 = g[f0] * rsqrtf(var[f0] + BN_EPS);
    float s1 = g[f0 + 1] * rsqrtf(var[f0 + 1] + BN_EPS);
    float y0 = (accx + b[f0] - mean[f0]) * s0 + beta[f0];
    float y1 = (accy + b[f0 + 1] - mean[f0 + 1]) * s1 + beta[f0 + 1];
    float2 o;
    o.x = fmaxf(y0, 0.f);
    o.y = fmaxf(y1, 0.f);
    reinterpret_cast<float2*>(out)[(size_t)node * 64 + lane] = o;
}

// F=64: one wave per node, 1 channel per lane. Fused bias+BN+ReLU, then
// fused GEMM3 (64 -> 2) via wave shuffle reduce. Writes h3[n][2] (no b3 yet).
__global__ __launch_bounds__(256)
void agg2_bnrelu_gemm3(const float* __restrict__ h, const float* __restrict__ dis,
                       const int* __restrict__ row_start, const int* __restrict__ csr,
                       const float* __restrict__ b, const float* __restrict__ g,
                       const float* __restrict__ beta, const float* __restrict__ mean,
                       const float* __restrict__ var, const float* __restrict__ w3,
                       float* __restrict__ h3, int n) {
    int node = (blockIdx.x * 256 + threadIdx.x) >> 6;
    int lane = threadIdx.x & 63;
    if (node >= n) return;
    float di = dis[node];
    float acc = h[(size_t)node * 64 + lane] * di * di;
    int rs = row_start[node], re = row_start[node + 1];
    for (int j = rs; j < re; ++j) {
        int s = csr[j];
        acc += h[(size_t)s * 64 + lane] * (dis[s] * di);
    }
    int f = lane;
    float sc = g[f] * rsqrtf(var[f] + BN_EPS);
    float y = (acc + b[f] - mean[f]) * sc + beta[f];
    y = fmaxf(y, 0.f);
    float r0 = y * w3[f * 2 + 0];
    float r1 = y * w3[f * 2 + 1];
    #pragma unroll
    for (int off = 32; off > 0; off >>= 1) {
        r0 += __shfl_down(r0, off);
        r1 += __shfl_down(r1, off);
    }
    if (lane == 0) {
        h3[(size_t)node * 2 + 0] = r0;
        h3[(size_t)node * 2 + 1] = r1;
    }
}

// F=2: one thread per node. Adds b3, writes final output.
__global__ void agg3(const float* __restrict__ h3, const float* __restrict__ dis,
                     const int* __restrict__ row_start, const int* __restrict__ csr,
                     const float* __restrict__ b3, float* __restrict__ out, int n) {
    int i = blockIdx.x * 256 + threadIdx.x;
    if (i >= n) return;
    float di = dis[i];
    const float2* hp = reinterpret_cast<const float2*>(h3);
    float2 hv = hp[i];
    float ax = hv.x * di * di;
    float ay = hv.y * di * di;
    int rs = row_start[i], re = row_start[i + 1];
    for (int j = rs; j < re; ++j) {
        int s = csr[j];
        float w = dis[s] * di;
        float2 v = hp[s];
        ax += v.x * w;
        ay += v.y * w;
    }
    out[(size_t)i * 2 + 0] = ax + b3[0];
    out[(size_t)i * 2 + 1] = ay + b3[1];
}

// ---------------- launch ----------------

extern "C" void kernel_launch(void* const* d_in, const int* in_sizes, int n_in,
                              void* d_out, int out_size, void* d_ws, size_t ws_size,
                              hipStream_t stream) {
    const float* x   = (const float*)d_in[0];
    const int*   ei  = (const int*)d_in[1];
    const float* w1  = (const float*)d_in[2];
    const float* b1  = (const float*)d_in[3];
    const float* g1  = (const float*)d_in[4];
    const float* bt1 = (const float*)d_in[5];
    const float* m1  = (const float*)d_in[6];
    const float* v1  = (const float*)d_in[7];
    const float* w2  = (const float*)d_in[8];
    const float* b2  = (const float*)d_in[9];
    const float* g2  = (const float*)d_in[10];
    const float* bt2 = (const float*)d_in[11];
    const float* m2  = (const float*)d_in[12];
    const float* v2  = (const float*)d_in[13];
    const float* w3  = (const float*)d_in[14];
    const float* b3  = (const float*)d_in[15];
    float* out = (float*)d_out;

    const int* srcp = ei;        // edge_index[0]
    const int* dstp = ei + NE;   // edge_index[1]

    char* ws = (char*)d_ws;
    int*   cnt       = (int*)(ws + 0);          // 200000 B
    int*   cursor    = (int*)(ws + 200064);     // 200000 B
    int*   row_start = (int*)(ws + 400128);     // 200004 B
    int*   csr       = (int*)(ws + 600192);     // 3200000 B
    float* dis       = (float*)(ws + 3800192);  // 200000 B
    float* h1        = (float*)(ws + 4000256);  // 25.6 MB  (50000 x 128)
    float* a1        = (float*)(ws + 29600256); // 25.6 MB  (50000 x 128)
    float* h2 = h1;   // reuse: h1 dead after agg1
    float* h3 = a1;   // reuse: a1 dead after gemm2 (only 50000 x 2 used)

    hipMemsetAsync(cnt, 0, NN * sizeof(int), stream);
    hipMemsetAsync(cursor, 0, NN * sizeof(int), stream);

    k_count<<<(NE + 255) / 256, 256, 0, stream>>>(dstp, cnt, NE);
    k_dis<<<(NN + 255) / 256, 256, 0, stream>>>(cnt, dis, NN);
    k_scan<<<1, 1024, 0, stream>>>(cnt, row_start, NN);
    k_fill<<<(NE + 255) / 256, 256, 0, stream>>>(srcp, dstp, row_start, cursor, csr, NE);

    // layer 1: h1 = x @ w1  [50000,512]x[512,128]
    gemm_f32<128, 128, 32, 8, 8>
        <<<dim3((NN + 127) / 128, 1), 256, 0, stream>>>(x, w1, h1, NN, 512, 128);
    // agg + bias + BN + ReLU -> a1
    agg1_bnrelu<<<(NN + 3) / 4, 256, 0, stream>>>(h1, dis, row_start, csr,
                                                  b1, g1, bt1, m1, v1, a1, NN);
    // layer 2: h2 = a1 @ w2  [50000,128]x[128,64]
    gemm_f32<64, 64, 32, 4, 4>
        <<<dim3((NN + 63) / 64, 1), 256, 0, stream>>>(a1, w2, h2, NN, 128, 64);
    // agg + bias + BN + ReLU + (h3 = a2 @ w3) fused
    agg2_bnrelu_gemm3<<<(NN + 3) / 4, 256, 0, stream>>>(h2, dis, row_start, csr,
                                                        b2, g2, bt2, m2, v2, w3, h3, NN);
    // layer 3 aggregation + b3 -> out
    agg3<<<(NN + 255) / 256, 256, 0, stream>>>(h3, dis, row_start, csr, b3, out, NN);
}

// Round 3
// 650.530 us; speedup vs baseline: 1.1044x; 1.1044x over previous
//
#include <hip/hip_runtime.h>

// DeepGCN: 3-layer GCN, N=50000, E=800000, 512->128->64->2, eval mode.
// Round 3: fp32 everywhere. GEMM1 re-tiled 64x64 for occupancy (was 9%).
// GEMM2 fused into agg1 epilogue (w2 staged in LDS). Wave-shuffle CSR scan.

constexpr int NN = 50000;
constexpr int NE = 800000;
constexpr float BN_EPS = 1e-5f;

// ---------------- CSR build ----------------

__global__ void k_count(const int* __restrict__ dst, int* __restrict__ cnt, int e) {
    int i = blockIdx.x * 256 + threadIdx.x;
    if (i < e) atomicAdd(&cnt[dst[i]], 1);
}

__global__ void k_dis(const int* __restrict__ cnt, float* __restrict__ dis, int n) {
    int i = blockIdx.x * 256 + threadIdx.x;
    if (i < n) dis[i] = rsqrtf((float)(cnt[i] + 1));   // +1 = self loop
}

// single-block scan, wave-shuffle based: 2 barriers per 1024-chunk.
__global__ __launch_bounds__(1024) void k_scan(const int* __restrict__ cnt,
                                               int* __restrict__ row_start, int n) {
    __shared__ int wsum[16];
    int tid = threadIdx.x;
    int lane = tid & 63, wv = tid >> 6;
    int running = 0;
    if (tid == 0) row_start[0] = 0;
    for (int base = 0; base < n; base += 1024) {
        int v = (base + tid < n) ? cnt[base + tid] : 0;
        #pragma unroll
        for (int off = 1; off < 64; off <<= 1) {
            int t = __shfl_up(v, off);
            if (lane >= off) v += t;
        }
        if (lane == 63) wsum[wv] = v;
        __syncthreads();
        int prefix = 0, total = 0;
        #pragma unroll
        for (int k = 0; k < 16; ++k) {
            int s = wsum[k];
            if (k < wv) prefix += s;
            total += s;
        }
        if (base + tid < n) row_start[base + tid + 1] = running + prefix + v;
        running += total;
        __syncthreads();   // protect wsum before next chunk
    }
}

__global__ void k_fill(const int* __restrict__ src, const int* __restrict__ dst,
                       const int* __restrict__ row_start, int* __restrict__ cursor,
                       int* __restrict__ csr, int e) {
    int i = blockIdx.x * 256 + threadIdx.x;
    if (i < e) {
        int d = dst[i];
        int pos = atomicAdd(&cursor[d], 1);
        csr[row_start[d] + pos] = src[i];
    }
}

// ---------------- tiled fp32 GEMM: C[M,Nn] = A[M,K] @ B[K,Nn] ----------------

template <int BM, int BN, int BK, int TM, int TN>
__global__ __launch_bounds__((BM / TM) * (BN / TN))
void gemm_f32(const float* __restrict__ A, const float* __restrict__ B,
              float* __restrict__ C, int M, int K, int Nn) {
    constexpr int TX = BN / TN;
    constexpr int TY = BM / TM;
    constexpr int NT = TX * TY;
    __shared__ float As[BK][BM + 4];
    __shared__ float Bs[BK][BN];
    const int bm = blockIdx.x * BM;
    const int bn = blockIdx.y * BN;
    const int tid = threadIdx.x;
    const int tx = tid % TX, ty = tid / TX;

    float acc[TM][TN] = {};

    for (int k0 = 0; k0 < K; k0 += BK) {
        #pragma unroll
        for (int i = tid; i < BM * BK / 4; i += NT) {
            int row = i / (BK / 4);
            int kk = (i % (BK / 4)) * 4;
            float4 v = make_float4(0.f, 0.f, 0.f, 0.f);
            if (bm + row < M)
                v = *reinterpret_cast<const float4*>(&A[(size_t)(bm + row) * K + k0 + kk]);
            As[kk + 0][row] = v.x;
            As[kk + 1][row] = v.y;
            As[kk + 2][row] = v.z;
            As[kk + 3][row] = v.w;
        }
        #pragma unroll
        for (int i = tid; i < BK * BN / 4; i += NT) {
            int kk = i / (BN / 4);
            int col = (i % (BN / 4)) * 4;
            *reinterpret_cast<float4*>(&Bs[kk][col]) =
                *reinterpret_cast<const float4*>(&B[(size_t)(k0 + kk) * Nn + bn + col]);
        }
        __syncthreads();

        #pragma unroll
        for (int kk = 0; kk < BK; ++kk) {
            float a[TM], b[TN];
            #pragma unroll
            for (int m = 0; m < TM; ++m) a[m] = As[kk][ty * TM + m];
            #pragma unroll
            for (int n2 = 0; n2 < TN; ++n2) b[n2] = Bs[kk][tx * TN + n2];
            #pragma unroll
            for (int m = 0; m < TM; ++m)
                #pragma unroll
                for (int n2 = 0; n2 < TN; ++n2) acc[m][n2] += a[m] * b[n2];
        }
        __syncthreads();
    }

    #pragma unroll
    for (int m = 0; m < TM; ++m) {
        int row = bm + ty * TM + m;
        if (row < M) {
            #pragma unroll
            for (int n2 = 0; n2 < TN; n2 += 4) {
                float4 v = {acc[m][n2], acc[m][n2 + 1], acc[m][n2 + 2], acc[m][n2 + 3]};
                *reinterpret_cast<float4*>(&C[(size_t)row * Nn + bn + tx * TN + n2]) = v;
            }
        }
    }
}

// ---------------- fused aggregation kernels ----------------
// agg(i) = dis[i]^2 * h[i] + sum_{s in N(i)} dis[s]*dis[i]*h[s]

// Layer-1 agg (F=128, one wave/node, float2/lane) + bias/BN/ReLU + GEMM2
// (128->64, w2 in LDS) fused. Writes h2[n][64].
__global__ __launch_bounds__(256)
void agg1_bn_gemm2(const float* __restrict__ h1, const float* __restrict__ dis,
                   const int* __restrict__ row_start, const int* __restrict__ csr,
                   const float* __restrict__ b1, const float* __restrict__ g1,
                   const float* __restrict__ beta1, const float* __restrict__ mean1,
                   const float* __restrict__ var1, const float* __restrict__ w2,
                   float* __restrict__ h2, int n) {
    __shared__ float w2s[128 * 64];
    __shared__ float a1s[4][130];
    int tid = threadIdx.x;
    // stage w2 (32 KB); latency overlaps with the gather below
    #pragma unroll
    for (int i = tid; i < 128 * 64 / 4; i += 256)
        reinterpret_cast<float4*>(w2s)[i] = reinterpret_cast<const float4*>(w2)[i];

    int node = (blockIdx.x * 256 + tid) >> 6;
    int lane = tid & 63;
    int wv = tid >> 6;

    if (node < n) {
        float di = dis[node];
        const float2* hp = reinterpret_cast<const float2*>(h1);
        float2 hv = hp[(size_t)node * 64 + lane];
        float accx = hv.x * di * di;
        float accy = hv.y * di * di;
        int rs = row_start[node], re = row_start[node + 1];
        for (int j = rs; j < re; ++j) {
            int s = csr[j];
            float w = dis[s] * di;
            float2 v = hp[(size_t)s * 64 + lane];
            accx += v.x * w;
            accy += v.y * w;
        }
        int f0 = lane * 2;
        float s0 = g1[f0] * rsqrtf(var1[f0] + BN_EPS);
        float s1 = g1[f0 + 1] * rsqrtf(var1[f0 + 1] + BN_EPS);
        float y0 = (accx + b1[f0] - mean1[f0]) * s0 + beta1[f0];
        float y1 = (accy + b1[f0 + 1] - mean1[f0 + 1]) * s1 + beta1[f0 + 1];
        a1s[wv][f0]     = fmaxf(y0, 0.f);
        a1s[wv][f0 + 1] = fmaxf(y1, 0.f);
    }
    __syncthreads();   // w2s staged + a1s rows written

    if (node < n) {
        float acc = 0.f;
        #pragma unroll
        for (int f = 0; f < 128; f += 4) {
            // broadcast reads of a1 row (uniform addr), coalesced w2s reads
            float a0 = a1s[wv][f + 0], a1v = a1s[wv][f + 1];
            float a2 = a1s[wv][f + 2], a3 = a1s[wv][f + 3];
            acc += a0 * w2s[(f + 0) * 64 + lane];
            acc += a1v * w2s[(f + 1) * 64 + lane];
            acc += a2 * w2s[(f + 2) * 64 + lane];
            acc += a3 * w2s[(f + 3) * 64 + lane];
        }
        h2[(size_t)node * 64 + lane] = acc;
    }
}

// Layer-2 agg (F=64, one wave/node) + bias/BN/ReLU + GEMM3 (64->2) fused.
__global__ __launch_bounds__(256)
void agg2_bnrelu_gemm3(const float* __restrict__ h, const float* __restrict__ dis,
                       const int* __restrict__ row_start, const int* __restrict__ csr,
                       const float* __restrict__ b, const float* __restrict__ g,
                       const float* __restrict__ beta, const float* __restrict__ mean,
                       const float* __restrict__ var, const float* __restrict__ w3,
                       float* __restrict__ h3, int n) {
    int node = (blockIdx.x * 256 + threadIdx.x) >> 6;
    int lane = threadIdx.x & 63;
    if (node >= n) return;
    float di = dis[node];
    float acc = h[(size_t)node * 64 + lane] * di * di;
    int rs = row_start[node], re = row_start[node + 1];
    for (int j = rs; j < re; ++j) {
        int s = csr[j];
        acc += h[(size_t)s * 64 + lane] * (dis[s] * di);
    }
    int f = lane;
    float sc = g[f] * rsqrtf(var[f] + BN_EPS);
    float y = (acc + b[f] - mean[f]) * sc + beta[f];
    y = fmaxf(y, 0.f);
    float r0 = y * w3[f * 2 + 0];
    float r1 = y * w3[f * 2 + 1];
    #pragma unroll
    for (int off = 32; off > 0; off >>= 1) {
        r0 += __shfl_down(r0, off);
        r1 += __shfl_down(r1, off);
    }
    if (lane == 0) {
        h3[(size_t)node * 2 + 0] = r0;
        h3[(size_t)node * 2 + 1] = r1;
    }
}

// Layer-3 agg (F=2, one thread/node) + b3 -> out.
__global__ void agg3(const float* __restrict__ h3, const float* __restrict__ dis,
                     const int* __restrict__ row_start, const int* __restrict__ csr,
                     const float* __restrict__ b3, float* __restrict__ out, int n) {
    int i = blockIdx.x * 256 + threadIdx.x;
    if (i >= n) return;
    float di = dis[i];
    const float2* hp = reinterpret_cast<const float2*>(h3);
    float2 hv = hp[i];
    float ax = hv.x * di * di;
    float ay = hv.y * di * di;
    int rs = row_start[i], re = row_start[i + 1];
    for (int j = rs; j < re; ++j) {
        int s = csr[j];
        float w = dis[s] * di;
        float2 v = hp[s];
        ax += v.x * w;
        ay += v.y * w;
    }
    out[(size_t)i * 2 + 0] = ax + b3[0];
    out[(size_t)i * 2 + 1] = ay + b3[1];
}

// ---------------- launch ----------------

extern "C" void kernel_launch(void* const* d_in, const int* in_sizes, int n_in,
                              void* d_out, int out_size, void* d_ws, size_t ws_size,
                              hipStream_t stream) {
    const float* x   = (const float*)d_in[0];
    const int*   ei  = (const int*)d_in[1];
    const float* w1  = (const float*)d_in[2];
    const float* b1  = (const float*)d_in[3];
    const float* g1  = (const float*)d_in[4];
    const float* bt1 = (const float*)d_in[5];
    const float* m1  = (const float*)d_in[6];
    const float* v1  = (const float*)d_in[7];
    const float* w2  = (const float*)d_in[8];
    const float* b2  = (const float*)d_in[9];
    const float* g2  = (const float*)d_in[10];
    const float* bt2 = (const float*)d_in[11];
    const float* m2  = (const float*)d_in[12];
    const float* v2  = (const float*)d_in[13];
    const float* w3  = (const float*)d_in[14];
    const float* b3  = (const float*)d_in[15];
    float* out = (float*)d_out;

    const int* srcp = ei;        // edge_index[0]
    const int* dstp = ei + NE;   // edge_index[1]

    char* ws = (char*)d_ws;
    int*   cnt       = (int*)(ws + 0);          // 200 KB
    int*   cursor    = (int*)(ws + 200064);
    int*   row_start = (int*)(ws + 400128);
    int*   csr       = (int*)(ws + 600192);     // 3.2 MB
    float* dis       = (float*)(ws + 3800192);
    float* h1        = (float*)(ws + 4000256);  // 25.6 MB (50000 x 128)
    float* h2        = (float*)(ws + 29600256); // 12.8 MB (50000 x 64)
    float* h3        = h1;                      // reuse: h1 dead after agg1_bn_gemm2

    hipMemsetAsync(cnt, 0, NN * sizeof(int), stream);
    hipMemsetAsync(cursor, 0, NN * sizeof(int), stream);

    k_count<<<(NE + 255) / 256, 256, 0, stream>>>(dstp, cnt, NE);
    k_dis<<<(NN + 255) / 256, 256, 0, stream>>>(cnt, dis, NN);
    k_scan<<<1, 1024, 0, stream>>>(cnt, row_start, NN);
    k_fill<<<(NE + 255) / 256, 256, 0, stream>>>(srcp, dstp, row_start, cursor, csr, NE);

    // layer 1 GEMM: h1 = x @ w1  [50000,512]x[512,128]; 64x64 tiles -> 1564 blocks
    gemm_f32<64, 64, 32, 4, 4>
        <<<dim3((NN + 63) / 64, 2), 256, 0, stream>>>(x, w1, h1, NN, 512, 128);
    // agg1 + bias/BN/ReLU + GEMM2 fused -> h2
    agg1_bn_gemm2<<<(NN + 3) / 4, 256, 0, stream>>>(h1, dis, row_start, csr,
                                                    b1, g1, bt1, m1, v1, w2, h2, NN);
    // agg2 + bias/BN/ReLU + GEMM3 fused -> h3
    agg2_bnrelu_gemm3<<<(NN + 3) / 4, 256, 0, stream>>>(h2, dis, row_start, csr,
                                                        b2, g2, bt2, m2, v2, w3, h3, NN);
    // layer-3 agg + b3 -> out
    agg3<<<(NN + 255) / 256, 256, 0, stream>>>(h3, dis, row_start, csr, b3, out, NN);
}

// Round 4
// 504.397 us; speedup vs baseline: 1.4243x; 1.2897x over previous
//
#include <hip/hip_runtime.h>
#include <hip/hip_fp16.h>

// DeepGCN: 3-layer GCN, N=50000, E=800000, 512->128->64->2, eval mode.
// Round 4: h1/h2 stored fp16 (gather bytes & L2 footprint halved; fp32 math).
// 4-wide MLP unroll in gather loops (latency chain /4). agg1 at 512 threads
// for 32 waves/CU. GEMM1 stays fp32 VALU, writes fp16.

constexpr int NN = 50000;
constexpr int NE = 800000;
constexpr float BN_EPS = 1e-5f;

// ---------------- CSR build ----------------

__global__ void k_count(const int* __restrict__ dst, int* __restrict__ cnt, int e) {
    int i = blockIdx.x * 256 + threadIdx.x;
    if (i < e) atomicAdd(&cnt[dst[i]], 1);
}

__global__ void k_dis(const int* __restrict__ cnt, float* __restrict__ dis, int n) {
    int i = blockIdx.x * 256 + threadIdx.x;
    if (i < n) dis[i] = rsqrtf((float)(cnt[i] + 1));   // +1 = self loop
}

// single-block scan, wave-shuffle based: 2 barriers per 1024-chunk.
__global__ __launch_bounds__(1024) void k_scan(const int* __restrict__ cnt,
                                               int* __restrict__ row_start, int n) {
    __shared__ int wsum[16];
    int tid = threadIdx.x;
    int lane = tid & 63, wv = tid >> 6;
    int running = 0;
    if (tid == 0) row_start[0] = 0;
    for (int base = 0; base < n; base += 1024) {
        int v = (base + tid < n) ? cnt[base + tid] : 0;
        #pragma unroll
        for (int off = 1; off < 64; off <<= 1) {
            int t = __shfl_up(v, off);
            if (lane >= off) v += t;
        }
        if (lane == 63) wsum[wv] = v;
        __syncthreads();
        int prefix = 0, total = 0;
        #pragma unroll
        for (int k = 0; k < 16; ++k) {
            int s = wsum[k];
            if (k < wv) prefix += s;
            total += s;
        }
        if (base + tid < n) row_start[base + tid + 1] = running + prefix + v;
        running += total;
        __syncthreads();   // protect wsum before next chunk
    }
}

__global__ void k_fill(const int* __restrict__ src, const int* __restrict__ dst,
                       const int* __restrict__ row_start, int* __restrict__ cursor,
                       int* __restrict__ csr, int e) {
    int i = blockIdx.x * 256 + threadIdx.x;
    if (i < e) {
        int d = dst[i];
        int pos = atomicAdd(&cursor[d], 1);
        csr[row_start[d] + pos] = src[i];
    }
}

// ------- tiled fp32 GEMM, fp16 output: C[M,Nn] = A[M,K] @ B[K,Nn] -------

template <int BM, int BN, int BK, int TM, int TN>
__global__ __launch_bounds__((BM / TM) * (BN / TN))
void gemm_f32_h16(const float* __restrict__ A, const float* __restrict__ B,
                  __half* __restrict__ C, int M, int K, int Nn) {
    constexpr int TX = BN / TN;
    constexpr int TY = BM / TM;
    constexpr int NT = TX * TY;
    __shared__ float As[BK][BM + 4];
    __shared__ float Bs[BK][BN];
    const int bm = blockIdx.x * BM;
    const int bn = blockIdx.y * BN;
    const int tid = threadIdx.x;
    const int tx = tid % TX, ty = tid / TX;

    float acc[TM][TN] = {};

    for (int k0 = 0; k0 < K; k0 += BK) {
        #pragma unroll
        for (int i = tid; i < BM * BK / 4; i += NT) {
            int row = i / (BK / 4);
            int kk = (i % (BK / 4)) * 4;
            float4 v = make_float4(0.f, 0.f, 0.f, 0.f);
            if (bm + row < M)
                v = *reinterpret_cast<const float4*>(&A[(size_t)(bm + row) * K + k0 + kk]);
            As[kk + 0][row] = v.x;
            As[kk + 1][row] = v.y;
            As[kk + 2][row] = v.z;
            As[kk + 3][row] = v.w;
        }
        #pragma unroll
        for (int i = tid; i < BK * BN / 4; i += NT) {
            int kk = i / (BN / 4);
            int col = (i % (BN / 4)) * 4;
            *reinterpret_cast<float4*>(&Bs[kk][col]) =
                *reinterpret_cast<const float4*>(&B[(size_t)(k0 + kk) * Nn + bn + col]);
        }
        __syncthreads();

        #pragma unroll
        for (int kk = 0; kk < BK; ++kk) {
            float a[TM], b[TN];
            #pragma unroll
            for (int m = 0; m < TM; ++m) a[m] = As[kk][ty * TM + m];
            #pragma unroll
            for (int n2 = 0; n2 < TN; ++n2) b[n2] = Bs[kk][tx * TN + n2];
            #pragma unroll
            for (int m = 0; m < TM; ++m)
                #pragma unroll
                for (int n2 = 0; n2 < TN; ++n2) acc[m][n2] += a[m] * b[n2];
        }
        __syncthreads();
    }

    #pragma unroll
    for (int m = 0; m < TM; ++m) {
        int row = bm + ty * TM + m;
        if (row < M) {
            static_assert(TN == 4, "epilogue assumes TN==4");
            __half2 p0 = __floats2half2_rn(acc[m][0], acc[m][1]);
            __half2 p1 = __floats2half2_rn(acc[m][2], acc[m][3]);
            __half2* cp = reinterpret_cast<__half2*>(&C[(size_t)row * Nn + bn + tx * TN]);
            cp[0] = p0;
            cp[1] = p1;
        }
    }
}

// ---------------- fused aggregation kernels ----------------
// agg(i) = dis[i]^2 * h[i] + sum_{s in N(i)} dis[s]*dis[i]*h[s]

// Layer-1 agg (F=128 fp16, one wave/node, half2/lane) + bias/BN/ReLU + GEMM2
// (128->64, w2 fp32 in LDS) fused. Writes h2[n][64] fp16. 512 thr = 8 nodes.
__global__ __launch_bounds__(512)
void agg1_bn_gemm2(const __half* __restrict__ h1, const float* __restrict__ dis,
                   const int* __restrict__ row_start, const int* __restrict__ csr,
                   const float* __restrict__ b1, const float* __restrict__ g1,
                   const float* __restrict__ beta1, const float* __restrict__ mean1,
                   const float* __restrict__ var1, const float* __restrict__ w2,
                   __half* __restrict__ h2, int n) {
    __shared__ float w2s[128 * 64];
    __shared__ float a1s[8][130];
    int tid = threadIdx.x;
    #pragma unroll
    for (int i = tid; i < 128 * 64 / 4; i += 512)
        reinterpret_cast<float4*>(w2s)[i] = reinterpret_cast<const float4*>(w2)[i];

    int node = (blockIdx.x * 512 + tid) >> 6;
    int lane = tid & 63;
    int wv = tid >> 6;

    if (node < n) {
        float di = dis[node];
        const __half2* hp = reinterpret_cast<const __half2*>(h1);
        float2 hv = __half22float2(hp[(size_t)node * 64 + lane]);
        float accx = hv.x * di * di;
        float accy = hv.y * di * di;
        int rs = row_start[node], re = row_start[node + 1];
        int j = rs;
        for (; j + 4 <= re; j += 4) {            // 4 independent chains -> MLP
            int s0 = csr[j], s1 = csr[j + 1], s2 = csr[j + 2], s3 = csr[j + 3];
            float u0 = dis[s0], u1 = dis[s1], u2 = dis[s2], u3 = dis[s3];
            __half2 v0 = hp[(size_t)s0 * 64 + lane];
            __half2 v1 = hp[(size_t)s1 * 64 + lane];
            __half2 v2 = hp[(size_t)s2 * 64 + lane];
            __half2 v3 = hp[(size_t)s3 * 64 + lane];
            float2 f0 = __half22float2(v0), f1 = __half22float2(v1);
            float2 f2 = __half22float2(v2), f3 = __half22float2(v3);
            accx += f0.x * (u0 * di) + f1.x * (u1 * di) + f2.x * (u2 * di) + f3.x * (u3 * di);
            accy += f0.y * (u0 * di) + f1.y * (u1 * di) + f2.y * (u2 * di) + f3.y * (u3 * di);
        }
        for (; j < re; ++j) {
            int s = csr[j];
            float w = dis[s] * di;
            float2 v = __half22float2(hp[(size_t)s * 64 + lane]);
            accx += v.x * w;
            accy += v.y * w;
        }
        int f0i = lane * 2;
        float s0 = g1[f0i] * rsqrtf(var1[f0i] + BN_EPS);
        float s1 = g1[f0i + 1] * rsqrtf(var1[f0i + 1] + BN_EPS);
        float y0 = (accx + b1[f0i] - mean1[f0i]) * s0 + beta1[f0i];
        float y1 = (accy + b1[f0i + 1] - mean1[f0i + 1]) * s1 + beta1[f0i + 1];
        a1s[wv][f0i]     = fmaxf(y0, 0.f);
        a1s[wv][f0i + 1] = fmaxf(y1, 0.f);
    }
    __syncthreads();   // w2s staged + a1s rows written

    if (node < n) {
        float acc = 0.f;
        #pragma unroll
        for (int f = 0; f < 128; f += 4) {
            float a0 = a1s[wv][f + 0], a1v = a1s[wv][f + 1];
            float a2 = a1s[wv][f + 2], a3 = a1s[wv][f + 3];
            acc += a0 * w2s[(f + 0) * 64 + lane];
            acc += a1v * w2s[(f + 1) * 64 + lane];
            acc += a2 * w2s[(f + 2) * 64 + lane];
            acc += a3 * w2s[(f + 3) * 64 + lane];
        }
        h2[(size_t)node * 64 + lane] = __float2half(acc);
    }
}

// Layer-2 agg (F=64 fp16, one wave/node) + bias/BN/ReLU + GEMM3 (64->2) fused.
__global__ __launch_bounds__(256)
void agg2_bnrelu_gemm3(const __half* __restrict__ h, const float* __restrict__ dis,
                       const int* __restrict__ row_start, const int* __restrict__ csr,
                       const float* __restrict__ b, const float* __restrict__ g,
                       const float* __restrict__ beta, const float* __restrict__ mean,
                       const float* __restrict__ var, const float* __restrict__ w3,
                       float* __restrict__ h3, int n) {
    int node = (blockIdx.x * 256 + threadIdx.x) >> 6;
    int lane = threadIdx.x & 63;
    if (node >= n) return;
    float di = dis[node];
    float acc = __half2float(h[(size_t)node * 64 + lane]) * di * di;
    int rs = row_start[node], re = row_start[node + 1];
    int j = rs;
    for (; j + 4 <= re; j += 4) {
        int s0 = csr[j], s1 = csr[j + 1], s2 = csr[j + 2], s3 = csr[j + 3];
        float u0 = dis[s0], u1 = dis[s1], u2 = dis[s2], u3 = dis[s3];
        float v0 = __half2float(h[(size_t)s0 * 64 + lane]);
        float v1 = __half2float(h[(size_t)s1 * 64 + lane]);
        float v2 = __half2float(h[(size_t)s2 * 64 + lane]);
        float v3 = __half2float(h[(size_t)s3 * 64 + lane]);
        acc += v0 * (u0 * di) + v1 * (u1 * di) + v2 * (u2 * di) + v3 * (u3 * di);
    }
    for (; j < re; ++j) {
        int s = csr[j];
        acc += __half2float(h[(size_t)s * 64 + lane]) * (dis[s] * di);
    }
    int f = lane;
    float sc = g[f] * rsqrtf(var[f] + BN_EPS);
    float y = (acc + b[f] - mean[f]) * sc + beta[f];
    y = fmaxf(y, 0.f);
    float r0 = y * w3[f * 2 + 0];
    float r1 = y * w3[f * 2 + 1];
    #pragma unroll
    for (int off = 32; off > 0; off >>= 1) {
        r0 += __shfl_down(r0, off);
        r1 += __shfl_down(r1, off);
    }
    if (lane == 0) {
        h3[(size_t)node * 2 + 0] = r0;
        h3[(size_t)node * 2 + 1] = r1;
    }
}

// Layer-3 agg (F=2, one thread/node) + b3 -> out.
__global__ void agg3(const float* __restrict__ h3, const float* __restrict__ dis,
                     const int* __restrict__ row_start, const int* __restrict__ csr,
                     const float* __restrict__ b3, float* __restrict__ out, int n) {
    int i = blockIdx.x * 256 + threadIdx.x;
    if (i >= n) return;
    float di = dis[i];
    const float2* hp = reinterpret_cast<const float2*>(h3);
    float2 hv = hp[i];
    float ax = hv.x * di * di;
    float ay = hv.y * di * di;
    int rs = row_start[i], re = row_start[i + 1];
    int j = rs;
    for (; j + 4 <= re; j += 4) {
        int s0 = csr[j], s1 = csr[j + 1], s2 = csr[j + 2], s3 = csr[j + 3];
        float u0 = dis[s0], u1 = dis[s1], u2 = dis[s2], u3 = dis[s3];
        float2 v0 = hp[s0], v1 = hp[s1], v2 = hp[s2], v3 = hp[s3];
        ax += v0.x * (u0 * di) + v1.x * (u1 * di) + v2.x * (u2 * di) + v3.x * (u3 * di);
        ay += v0.y * (u0 * di) + v1.y * (u1 * di) + v2.y * (u2 * di) + v3.y * (u3 * di);
    }
    for (; j < re; ++j) {
        int s = csr[j];
        float w = dis[s] * di;
        float2 v = hp[s];
        ax += v.x * w;
        ay += v.y * w;
    }
    out[(size_t)i * 2 + 0] = ax + b3[0];
    out[(size_t)i * 2 + 1] = ay + b3[1];
}

// ---------------- launch ----------------

extern "C" void kernel_launch(void* const* d_in, const int* in_sizes, int n_in,
                              void* d_out, int out_size, void* d_ws, size_t ws_size,
                              hipStream_t stream) {
    const float* x   = (const float*)d_in[0];
    const int*   ei  = (const int*)d_in[1];
    const float* w1  = (const float*)d_in[2];
    const float* b1  = (const float*)d_in[3];
    const float* g1  = (const float*)d_in[4];
    const float* bt1 = (const float*)d_in[5];
    const float* m1  = (const float*)d_in[6];
    const float* v1  = (const float*)d_in[7];
    const float* w2  = (const float*)d_in[8];
    const float* b2  = (const float*)d_in[9];
    const float* g2  = (const float*)d_in[10];
    const float* bt2 = (const float*)d_in[11];
    const float* m2  = (const float*)d_in[12];
    const float* v2  = (const float*)d_in[13];
    const float* w3  = (const float*)d_in[14];
    const float* b3  = (const float*)d_in[15];
    float* out = (float*)d_out;

    const int* srcp = ei;        // edge_index[0]
    const int* dstp = ei + NE;   // edge_index[1]

    char* ws = (char*)d_ws;
    int*    cnt       = (int*)(ws + 0);          // 200 KB
    int*    cursor    = (int*)(ws + 200064);
    int*    row_start = (int*)(ws + 400128);
    int*    csr       = (int*)(ws + 600192);     // 3.2 MB
    float*  dis       = (float*)(ws + 3800192);
    __half* h1        = (__half*)(ws + 4000256); // 12.8 MB (50000 x 128 fp16)
    __half* h2        = (__half*)(ws + 16800512);// 6.4 MB  (50000 x 64 fp16)
    float*  h3        = (float*)(ws + 23200512); // 400 KB  (50000 x 2 fp32)

    hipMemsetAsync(cnt, 0, NN * sizeof(int), stream);
    hipMemsetAsync(cursor, 0, NN * sizeof(int), stream);

    k_count<<<(NE + 255) / 256, 256, 0, stream>>>(dstp, cnt, NE);
    k_dis<<<(NN + 255) / 256, 256, 0, stream>>>(cnt, dis, NN);
    k_scan<<<1, 1024, 0, stream>>>(cnt, row_start, NN);
    k_fill<<<(NE + 255) / 256, 256, 0, stream>>>(srcp, dstp, row_start, cursor, csr, NE);

    // layer 1 GEMM: h1 = fp16(x @ w1)  [50000,512]x[512,128]; 64x64 tiles
    gemm_f32_h16<64, 64, 32, 4, 4>
        <<<dim3((NN + 63) / 64, 2), 256, 0, stream>>>(x, w1, h1, NN, 512, 128);
    // agg1 + bias/BN/ReLU + GEMM2 fused -> h2 (fp16)
    agg1_bn_gemm2<<<(NN * 64 + 511) / 512, 512, 0, stream>>>(h1, dis, row_start, csr,
                                                             b1, g1, bt1, m1, v1, w2, h2, NN);
    // agg2 + bias/BN/ReLU + GEMM3 fused -> h3
    agg2_bnrelu_gemm3<<<(NN + 3) / 4, 256, 0, stream>>>(h2, dis, row_start, csr,
                                                        b2, g2, bt2, m2, v2, w3, h3, NN);
    // layer-3 agg + b3 -> out
    agg3<<<(NN + 255) / 256, 256, 0, stream>>>(h3, dis, row_start, csr, b3, out, NN);
}

// Round 5
// 451.378 us; speedup vs baseline: 1.5916x; 1.1175x over previous
//
#include <hip/hip_runtime.h>
#include <hip/hip_fp16.h>

// DeepGCN: 3-layer GCN, N=50000, E=800000, 512->128->64->2, eval mode.
// Round 5: GEMM1 on fp16 MFMA (fp32 accum). dis[] folded into stored
// features (h1'=dis*h1 etc) so agg loops are pure csr->row chains.
// Masked unroll-8 gathers, readfirstlane for SGPR bases, BN prep kernel.

constexpr int NN = 50000;
constexpr int NE = 800000;
constexpr float BN_EPS = 1e-5f;

using f16x8 = __attribute__((ext_vector_type(8))) _Float16;
using f32x4 = __attribute__((ext_vector_type(4))) float;

// ---------- prep: w1 -> w1t fp16 transposed [128][512]; BN scale/shift ----------
__global__ void k_prep(const float* __restrict__ w1,
                       const float* __restrict__ b1, const float* __restrict__ g1,
                       const float* __restrict__ beta1, const float* __restrict__ m1,
                       const float* __restrict__ v1,
                       const float* __restrict__ b2, const float* __restrict__ g2,
                       const float* __restrict__ beta2, const float* __restrict__ m2,
                       const float* __restrict__ v2,
                       __half* __restrict__ w1t,
                       float* __restrict__ bns1, float* __restrict__ bnb1,
                       float* __restrict__ bns2, float* __restrict__ bnb2) {
    int i = blockIdx.x * 256 + threadIdx.x;
    if (i < 512 * 128) {
        int k = i >> 7, n = i & 127;
        w1t[n * 512 + k] = __float2half(w1[i]);
    } else if (i < 512 * 128 + 128) {
        int f = i - 512 * 128;
        float s = g1[f] * rsqrtf(v1[f] + BN_EPS);
        bns1[f] = s;
        bnb1[f] = (b1[f] - m1[f]) * s + beta1[f];
    } else if (i < 512 * 128 + 128 + 64) {
        int f = i - (512 * 128 + 128);
        float s = g2[f] * rsqrtf(v2[f] + BN_EPS);
        bns2[f] = s;
        bnb2[f] = (b2[f] - m2[f]) * s + beta2[f];
    }
}

// ---------------- CSR build ----------------

__global__ void k_count(const int* __restrict__ dst, int* __restrict__ cnt, int e) {
    int i = blockIdx.x * 256 + threadIdx.x;
    if (i < e) atomicAdd(&cnt[dst[i]], 1);
}

// single-block scan (wave-shuffle) + dis = rsqrt(cnt+1)
__global__ __launch_bounds__(1024) void k_scan(const int* __restrict__ cnt,
                                               int* __restrict__ row_start,
                                               float* __restrict__ dis, int n) {
    __shared__ int wsum[16];
    int tid = threadIdx.x;
    int lane = tid & 63, wv = tid >> 6;
    int running = 0;
    if (tid == 0) row_start[0] = 0;
    for (int base = 0; base < n; base += 1024) {
        int c = (base + tid < n) ? cnt[base + tid] : 0;
        if (base + tid < n) dis[base + tid] = rsqrtf((float)(c + 1));
        int v = c;
        #pragma unroll
        for (int off = 1; off < 64; off <<= 1) {
            int t = __shfl_up(v, off);
            if (lane >= off) v += t;
        }
        if (lane == 63) wsum[wv] = v;
        __syncthreads();
        int prefix = 0, total = 0;
        #pragma unroll
        for (int k = 0; k < 16; ++k) {
            int s = wsum[k];
            if (k < wv) prefix += s;
            total += s;
        }
        if (base + tid < n) row_start[base + tid + 1] = running + prefix + v;
        running += total;
        __syncthreads();
    }
}

// fill via atomicSub on cnt (counts consumed to zero; no cursor buffer)
__global__ void k_fill(const int* __restrict__ src, const int* __restrict__ dst,
                       const int* __restrict__ row_start, int* __restrict__ cnt,
                       int* __restrict__ csr, int e) {
    int i = blockIdx.x * 256 + threadIdx.x;
    if (i < e) {
        int d = dst[i];
        int pos = atomicSub(&cnt[d], 1) - 1;
        csr[row_start[d] + pos] = src[i];
    }
}

// -------- GEMM1: h1' = fp16( (x @ w1) * dis[row] ), fp16 MFMA --------
// block 256 thr = 4 waves (2m x 2n). Tile 32(M) x 128(N), BK=32, K=512.
// A: fp32->fp16 staged in LDS (pad to 40 halfs/row, 16B-aligned frags).
// B: fragments loaded directly from L2-resident w1t[128][512].
__global__ __launch_bounds__(256)
void gemm1_mfma(const float* __restrict__ x, const __half* __restrict__ w1t,
                const float* __restrict__ dis, __half* __restrict__ h1, int M) {
    __shared__ __half As[32][40];
    int tid = threadIdx.x, lane = tid & 63, wv = tid >> 6;
    int bm = blockIdx.x * 32;
    int mh = wv >> 1, nh = wv & 1;

    f32x4 acc[4] = {f32x4{0,0,0,0}, f32x4{0,0,0,0}, f32x4{0,0,0,0}, f32x4{0,0,0,0}};

    const int arow = mh * 16 + (lane & 15);
    const int kgrp = (lane >> 4) * 8;
    const int sr = tid >> 3;
    const int sc = (tid & 7) * 4;
    const bool arow_ok = (bm + sr) < M;
    const float* xrow = x + (size_t)(bm + sr) * 512 + sc;

    for (int k0 = 0; k0 < 512; k0 += 32) {
        float4 v = make_float4(0.f, 0.f, 0.f, 0.f);
        if (arow_ok) v = *reinterpret_cast<const float4*>(xrow + k0);
        __half2* d2 = reinterpret_cast<__half2*>(&As[sr][sc]);
        d2[0] = __floats2half2_rn(v.x, v.y);
        d2[1] = __floats2half2_rn(v.z, v.w);
        __syncthreads();

        f16x8 af = *reinterpret_cast<const f16x8*>(&As[arow][kgrp]);
        #pragma unroll
        for (int t = 0; t < 4; ++t) {
            int col = nh * 64 + t * 16 + (lane & 15);
            f16x8 bf = *reinterpret_cast<const f16x8*>(&w1t[(size_t)col * 512 + k0 + kgrp]);
            acc[t] = __builtin_amdgcn_mfma_f32_16x16x32_f16(af, bf, acc[t], 0, 0, 0);
        }
        __syncthreads();
    }

    // C/D: col = lane&15 (within tile), row = (lane>>4)*4 + reg  [m89-verified]
    #pragma unroll
    for (int j = 0; j < 4; ++j) {
        int row = bm + mh * 16 + (lane >> 4) * 4 + j;
        if (row < M) {
            float dv = dis[row];
            #pragma unroll
            for (int t = 0; t < 4; ++t) {
                int col = nh * 64 + t * 16 + (lane & 15);
                h1[(size_t)row * 128 + col] = __float2half(acc[t][j] * dv);
            }
        }
    }
}

// ---------------- fused aggregation ----------------
// With folded features: agg(i) = di * ( h'[i] + sum_{s in N(i)} h'[s] )

// agg1 (F=128 fp16, wave/node) + BN/ReLU + GEMM2 (w2 in LDS) -> h2' fp16
__global__ __launch_bounds__(512)
void agg1_bn_gemm2(const __half* __restrict__ h1, const float* __restrict__ dis,
                   const int* __restrict__ row_start, const int* __restrict__ csr,
                   const float* __restrict__ bns1, const float* __restrict__ bnb1,
                   const float* __restrict__ w2, __half* __restrict__ h2, int n) {
    __shared__ float w2s[128 * 64];
    __shared__ float a1s[8][130];
    int tid = threadIdx.x;
    for (int i = tid; i < 128 * 64 / 4; i += 512)
        reinterpret_cast<float4*>(w2s)[i] = reinterpret_cast<const float4*>(w2)[i];

    int node = (blockIdx.x * 512 + tid) >> 6;
    int lane = tid & 63;
    int wv = tid >> 6;
    float di = 0.f;

    if (node < n) {
        int nd = __builtin_amdgcn_readfirstlane(node);
        di = dis[nd];
        const __half2* hp = reinterpret_cast<const __half2*>(h1);
        float2 hv = __half22float2(hp[(size_t)nd * 64 + lane]);
        float accx = hv.x, accy = hv.y;
        int rs = row_start[nd], re = row_start[nd + 1];
        for (int j = rs; j < re; j += 8) {
            #pragma unroll
            for (int u = 0; u < 8; ++u) {
                int jj = j + u;
                int s = __builtin_amdgcn_readfirstlane(csr[jj < re ? jj : re - 1]);
                float msk = (jj < re) ? 1.f : 0.f;
                float2 f = __half22float2(hp[(size_t)s * 64 + lane]);
                accx += msk * f.x;
                accy += msk * f.y;
            }
        }
        int f0 = lane * 2;
        float y0 = fmaxf(accx * (di * bns1[f0])     + bnb1[f0],     0.f);
        float y1 = fmaxf(accy * (di * bns1[f0 + 1]) + bnb1[f0 + 1], 0.f);
        a1s[wv][f0]     = y0;
        a1s[wv][f0 + 1] = y1;
    }
    __syncthreads();   // w2s staged + a1s written

    if (node < n) {
        float acc = 0.f;
        #pragma unroll
        for (int f = 0; f < 128; f += 4) {
            float a0 = a1s[wv][f + 0], a1v = a1s[wv][f + 1];
            float a2 = a1s[wv][f + 2], a3 = a1s[wv][f + 3];
            acc += a0 * w2s[(f + 0) * 64 + lane];
            acc += a1v * w2s[(f + 1) * 64 + lane];
            acc += a2 * w2s[(f + 2) * 64 + lane];
            acc += a3 * w2s[(f + 3) * 64 + lane];
        }
        h2[(size_t)node * 64 + lane] = __float2half(acc * di);   // fold dis for agg2
    }
}

// agg2 (F=64 fp16, wave/node) + BN/ReLU + GEMM3 (64->2 wave reduce) -> h3' fp32
__global__ __launch_bounds__(256)
void agg2_bnrelu_gemm3(const __half* __restrict__ h2, const float* __restrict__ dis,
                       const int* __restrict__ row_start, const int* __restrict__ csr,
                       const float* __restrict__ bns2, const float* __restrict__ bnb2,
                       const float* __restrict__ w3, float* __restrict__ h3, int n) {
    int node = (blockIdx.x * 256 + threadIdx.x) >> 6;
    int lane = threadIdx.x & 63;
    if (node >= n) return;
    int nd = __builtin_amdgcn_readfirstlane(node);
    float di = dis[nd];
    float acc = __half2float(h2[(size_t)nd * 64 + lane]);
    int rs = row_start[nd], re = row_start[nd + 1];
    for (int j = rs; j < re; j += 8) {
        #pragma unroll
        for (int u = 0; u < 8; ++u) {
            int jj = j + u;
            int s = __builtin_amdgcn_readfirstlane(csr[jj < re ? jj : re - 1]);
            float msk = (jj < re) ? 1.f : 0.f;
            acc += msk * __half2float(h2[(size_t)s * 64 + lane]);
        }
    }
    float y = fmaxf(acc * (di * bns2[lane]) + bnb2[lane], 0.f);
    float r0 = y * w3[lane * 2 + 0];
    float r1 = y * w3[lane * 2 + 1];
    #pragma unroll
    for (int off = 32; off > 0; off >>= 1) {
        r0 += __shfl_down(r0, off);
        r1 += __shfl_down(r1, off);
    }
    if (lane == 0) {
        h3[(size_t)nd * 2 + 0] = r0 * di;   // fold dis for agg3
        h3[(size_t)nd * 2 + 1] = r1 * di;
    }
}

// agg3 (F=2, thread/node) + b3 -> out
__global__ void agg3(const float* __restrict__ h3, const float* __restrict__ dis,
                     const int* __restrict__ row_start, const int* __restrict__ csr,
                     const float* __restrict__ b3, float* __restrict__ out, int n) {
    int i = blockIdx.x * 256 + threadIdx.x;
    if (i >= n) return;
    float di = dis[i];
    const float2* hp = reinterpret_cast<const float2*>(h3);
    float2 hv = hp[i];
    float ax = hv.x, ay = hv.y;
    int rs = row_start[i], re = row_start[i + 1];
    for (int j = rs; j < re; j += 8) {
        #pragma unroll
        for (int u = 0; u < 8; ++u) {
            int jj = j + u;
            int s = csr[jj < re ? jj : re - 1];
            float msk = (jj < re) ? 1.f : 0.f;
            float2 v = hp[s];
            ax += msk * v.x;
            ay += msk * v.y;
        }
    }
    out[(size_t)i * 2 + 0] = ax * di + b3[0];
    out[(size_t)i * 2 + 1] = ay * di + b3[1];
}

// ---------------- launch ----------------

extern "C" void kernel_launch(void* const* d_in, const int* in_sizes, int n_in,
                              void* d_out, int out_size, void* d_ws, size_t ws_size,
                              hipStream_t stream) {
    const float* x   = (const float*)d_in[0];
    const int*   ei  = (const int*)d_in[1];
    const float* w1  = (const float*)d_in[2];
    const float* b1  = (const float*)d_in[3];
    const float* g1  = (const float*)d_in[4];
    const float* bt1 = (const float*)d_in[5];
    const float* m1  = (const float*)d_in[6];
    const float* v1  = (const float*)d_in[7];
    const float* w2  = (const float*)d_in[8];
    const float* b2  = (const float*)d_in[9];
    const float* g2  = (const float*)d_in[10];
    const float* bt2 = (const float*)d_in[11];
    const float* m2  = (const float*)d_in[12];
    const float* v2  = (const float*)d_in[13];
    const float* w3  = (const float*)d_in[14];
    const float* b3  = (const float*)d_in[15];
    float* out = (float*)d_out;

    const int* srcp = ei;        // edge_index[0]
    const int* dstp = ei + NE;   // edge_index[1]

    char* ws = (char*)d_ws;
    int*    cnt       = (int*)(ws + 0);            // 200 KB
    int*    row_start = (int*)(ws + 200064);       // 200 KB
    int*    csr       = (int*)(ws + 400128);       // 3.2 MB
    float*  dis       = (float*)(ws + 3600192);    // 200 KB
    __half* w1t       = (__half*)(ws + 3800256);   // 128 KB fp16 [128][512]
    float*  bns1      = (float*)(ws + 3931392);    // 512 B
    float*  bnb1      = (float*)(ws + 3931904);
    float*  bns2      = (float*)(ws + 3932416);    // 256 B
    float*  bnb2      = (float*)(ws + 3932672);
    __half* h1        = (__half*)(ws + 4000256);   // 12.8 MB (50000 x 128 fp16)
    __half* h2        = (__half*)(ws + 16800512);  // 6.4 MB  (50000 x 64 fp16)
    float*  h3        = (float*)(ws + 23200512);   // 400 KB  (50000 x 2 fp32)

    hipMemsetAsync(cnt, 0, NN * sizeof(int), stream);

    k_prep<<<(512 * 128 + 192 + 255) / 256, 256, 0, stream>>>(
        w1, b1, g1, bt1, m1, v1, b2, g2, bt2, m2, v2, w1t, bns1, bnb1, bns2, bnb2);
    k_count<<<(NE + 255) / 256, 256, 0, stream>>>(dstp, cnt, NE);
    k_scan<<<1, 1024, 0, stream>>>(cnt, row_start, dis, NN);
    k_fill<<<(NE + 255) / 256, 256, 0, stream>>>(srcp, dstp, row_start, cnt, csr, NE);

    // h1' = fp16((x @ w1) * dis)
    gemm1_mfma<<<(NN + 31) / 32, 256, 0, stream>>>(x, w1t, dis, h1, NN);
    // agg1 + BN/ReLU + GEMM2 -> h2'
    agg1_bn_gemm2<<<(NN * 64 + 511) / 512, 512, 0, stream>>>(
        h1, dis, row_start, csr, bns1, bnb1, w2, h2, NN);
    // agg2 + BN/ReLU + GEMM3 -> h3'
    agg2_bnrelu_gemm3<<<(NN * 64 + 255) / 256, 256, 0, stream>>>(
        h2, dis, row_start, csr, bns2, bnb2, w3, h3, NN);
    // agg3 + b3 -> out
    agg3<<<(NN + 255) / 256, 256, 0, stream>>>(h3, dis, row_start, csr, b3, out, NN);
}

// Round 6
// 403.011 us; speedup vs baseline: 1.7826x; 1.1200x over previous
//
#include <hip/hip_runtime.h>
#include <hip/hip_fp16.h>

// DeepGCN: 3-layer GCN, N=50000, E=800000, 512->128->64->2, eval mode.
// Round 6: w1/w2 pre-packed into MFMA fragment order (coalesced B loads);
// GEMM2 unfused from agg1 (the 128 ds_read_b32/node matvec was ~60us) and
// done as its own MFMA kernel; agg1 is now a pure gather (no LDS, VGPR=16).

constexpr int NN = 50000;
constexpr int NE = 800000;
constexpr float BN_EPS = 1e-5f;

using f16x8 = __attribute__((ext_vector_type(8))) _Float16;
using f32x4 = __attribute__((ext_vector_type(4))) float;

// ---------- prep: pack w1/w2 to fragment order; BN scale/shift ----------
// w1f slot layout: ((ks*2 + nh)*4 + t)*64 + lane, elem j:
//   n = nh*64 + t*16 + (lane&15), k = ks*32 + (lane>>4)*8 + j
// w2f slot layout: (ks*4 + t)*64 + lane, elem j:
//   n = t*16 + (lane&15),        k = ks*32 + (lane>>4)*8 + j
__global__ void k_prep(const float* __restrict__ w1, const float* __restrict__ w2,
                       const float* __restrict__ b1, const float* __restrict__ g1,
                       const float* __restrict__ beta1, const float* __restrict__ m1,
                       const float* __restrict__ v1,
                       const float* __restrict__ b2, const float* __restrict__ g2,
                       const float* __restrict__ beta2, const float* __restrict__ m2,
                       const float* __restrict__ v2,
                       __half* __restrict__ w1f, __half* __restrict__ w2f,
                       float* __restrict__ bns1, float* __restrict__ bnb1,
                       float* __restrict__ bns2, float* __restrict__ bnb2) {
    int i = blockIdx.x * 256 + threadIdx.x;
    if (i < 512 * 128) {                     // w1 [512][128]
        int k = i >> 7, n = i & 127;
        int ks = k >> 5, hi = (k & 31) >> 3, j = k & 7;
        int nh = n >> 6, t = (n >> 4) & 3;
        int lane = hi * 16 + (n & 15);
        int slot = ((ks * 2 + nh) * 4 + t) * 64 + lane;
        w1f[slot * 8 + j] = __float2half(w1[i]);
    } else if (i < 512 * 128 + 128 * 64) {   // w2 [128][64]
        int i2 = i - 512 * 128;
        int k = i2 >> 6, n = i2 & 63;
        int ks = k >> 5, hi = (k & 31) >> 3, j = k & 7;
        int t = n >> 4;
        int lane = hi * 16 + (n & 15);
        int slot = (ks * 4 + t) * 64 + lane;
        w2f[slot * 8 + j] = __float2half(w2[i2]);
    } else if (i < 512 * 128 + 128 * 64 + 128) {
        int f = i - (512 * 128 + 128 * 64);
        float s = g1[f] * rsqrtf(v1[f] + BN_EPS);
        bns1[f] = s;
        bnb1[f] = (b1[f] - m1[f]) * s + beta1[f];
    } else if (i < 512 * 128 + 128 * 64 + 128 + 64) {
        int f = i - (512 * 128 + 128 * 64 + 128);
        float s = g2[f] * rsqrtf(v2[f] + BN_EPS);
        bns2[f] = s;
        bnb2[f] = (b2[f] - m2[f]) * s + beta2[f];
    }
}

// ---------------- CSR build ----------------

__global__ void k_count(const int* __restrict__ dst, int* __restrict__ cnt, int e) {
    int i = blockIdx.x * 256 + threadIdx.x;
    if (i < e) atomicAdd(&cnt[dst[i]], 1);
}

__global__ __launch_bounds__(1024) void k_scan(const int* __restrict__ cnt,
                                               int* __restrict__ row_start,
                                               float* __restrict__ dis, int n) {
    __shared__ int wsum[16];
    int tid = threadIdx.x;
    int lane = tid & 63, wv = tid >> 6;
    int running = 0;
    if (tid == 0) row_start[0] = 0;
    for (int base = 0; base < n; base += 1024) {
        int c = (base + tid < n) ? cnt[base + tid] : 0;
        if (base + tid < n) dis[base + tid] = rsqrtf((float)(c + 1));
        int v = c;
        #pragma unroll
        for (int off = 1; off < 64; off <<= 1) {
            int t = __shfl_up(v, off);
            if (lane >= off) v += t;
        }
        if (lane == 63) wsum[wv] = v;
        __syncthreads();
        int prefix = 0, total = 0;
        #pragma unroll
        for (int k = 0; k < 16; ++k) {
            int s = wsum[k];
            if (k < wv) prefix += s;
            total += s;
        }
        if (base + tid < n) row_start[base + tid + 1] = running + prefix + v;
        running += total;
        __syncthreads();
    }
}

__global__ void k_fill(const int* __restrict__ src, const int* __restrict__ dst,
                       const int* __restrict__ row_start, int* __restrict__ cnt,
                       int* __restrict__ csr, int e) {
    int i = blockIdx.x * 256 + threadIdx.x;
    if (i < e) {
        int d = dst[i];
        int pos = atomicSub(&cnt[d], 1) - 1;
        csr[row_start[d] + pos] = src[i];
    }
}

// -------- GEMM1: h1' = fp16( (x @ w1) * dis[row] ), fp16 MFMA --------
// 256 thr = 4 waves (2m x 2n); tile 32M x 128N; BK=32, K=512.
// x tile reg-double-buffered through LDS; B frags coalesced from w1f.
__global__ __launch_bounds__(256)
void gemm1_mfma(const float* __restrict__ x, const __half* __restrict__ w1f,
                const float* __restrict__ dis, __half* __restrict__ h1, int M) {
    __shared__ __half As[32][40];
    int tid = threadIdx.x, lane = tid & 63, wv = tid >> 6;
    int bm = blockIdx.x * 32;
    int mh = wv >> 1, nh = wv & 1;

    f32x4 acc[4] = {f32x4{0,0,0,0}, f32x4{0,0,0,0}, f32x4{0,0,0,0}, f32x4{0,0,0,0}};

    const int arow = mh * 16 + (lane & 15);
    const int kgrp = (lane >> 4) * 8;
    const int sr = tid >> 3;
    const int sc = (tid & 7) * 4;
    const bool arow_ok = (bm + sr) < M;
    const float* xrow = x + (size_t)(bm + sr) * 512 + sc;

    float4 cur = make_float4(0.f, 0.f, 0.f, 0.f);
    if (arow_ok) cur = *reinterpret_cast<const float4*>(xrow);

    for (int ks = 0; ks < 16; ++ks) {
        __half2* d2 = reinterpret_cast<__half2*>(&As[sr][sc]);
        d2[0] = __floats2half2_rn(cur.x, cur.y);
        d2[1] = __floats2half2_rn(cur.z, cur.w);
        __syncthreads();

        float4 nxt = make_float4(0.f, 0.f, 0.f, 0.f);
        if (ks < 15 && arow_ok)
            nxt = *reinterpret_cast<const float4*>(xrow + (ks + 1) * 32);

        f16x8 af = *reinterpret_cast<const f16x8*>(&As[arow][kgrp]);
        #pragma unroll
        for (int t = 0; t < 4; ++t) {
            int slot = ((ks * 2 + nh) * 4 + t) * 64 + lane;
            f16x8 bf = *reinterpret_cast<const f16x8*>(&w1f[slot * 8]);
            acc[t] = __builtin_amdgcn_mfma_f32_16x16x32_f16(af, bf, acc[t], 0, 0, 0);
        }
        __syncthreads();
        cur = nxt;
    }

    #pragma unroll
    for (int j = 0; j < 4; ++j) {
        int row = bm + mh * 16 + (lane >> 4) * 4 + j;
        if (row < M) {
            float dv = dis[row];
            #pragma unroll
            for (int t = 0; t < 4; ++t) {
                int col = nh * 64 + t * 16 + (lane & 15);
                h1[(size_t)row * 128 + col] = __float2half(acc[t][j] * dv);
            }
        }
    }
}

// -------- agg1: a1 = ReLU(BN( di * (h1'[i] + sum h1'[s]) )), pure gather --------
__global__ __launch_bounds__(512)
void agg1_bn(const __half* __restrict__ h1, const float* __restrict__ dis,
             const int* __restrict__ row_start, const int* __restrict__ csr,
             const float* __restrict__ bns1, const float* __restrict__ bnb1,
             __half* __restrict__ a1, int n) {
    int node = (blockIdx.x * 512 + threadIdx.x) >> 6;
    int lane = threadIdx.x & 63;
    if (node >= n) return;
    int nd = __builtin_amdgcn_readfirstlane(node);
    float di = dis[nd];
    const __half2* hp = reinterpret_cast<const __half2*>(h1);
    float2 hv = __half22float2(hp[(size_t)nd * 64 + lane]);
    float accx = hv.x, accy = hv.y;
    int rs = row_start[nd], re = row_start[nd + 1];
    for (int j = rs; j < re; j += 8) {
        #pragma unroll
        for (int u = 0; u < 8; ++u) {
            int jj = j + u;
            int s = __builtin_amdgcn_readfirstlane(csr[jj < re ? jj : re - 1]);
            float msk = (jj < re) ? 1.f : 0.f;
            float2 f = __half22float2(hp[(size_t)s * 64 + lane]);
            accx += msk * f.x;
            accy += msk * f.y;
        }
    }
    int f0 = lane * 2;
    float y0 = fmaxf(accx * (di * bns1[f0])     + bnb1[f0],     0.f);
    float y1 = fmaxf(accy * (di * bns1[f0 + 1]) + bnb1[f0 + 1], 0.f);
    reinterpret_cast<__half2*>(a1)[(size_t)nd * 64 + lane] = __floats2half2_rn(y0, y1);
}

// -------- GEMM2: h2' = fp16( (a1 @ w2) * dis[row] ), fp16 MFMA --------
// 256 thr = 4 waves (4m); tile 64M x 64N; K=128 (4 steps). Single barrier.
__global__ __launch_bounds__(256)
void gemm2_mfma(const __half* __restrict__ a1, const __half* __restrict__ w2f,
                const float* __restrict__ dis, __half* __restrict__ h2, int M) {
    __shared__ __half As[64][136];
    int tid = threadIdx.x, lane = tid & 63, wv = tid >> 6;
    int bm = blockIdx.x * 64;

    #pragma unroll
    for (int p = 0; p < 4; ++p) {
        int idx = tid + p * 256;            // 1024 x 16B = 64 rows x 256B
        int row = idx >> 4;
        int col = (idx & 15) * 8;
        f16x8 v = {};
        if (bm + row < M)
            v = *reinterpret_cast<const f16x8*>(&a1[(size_t)(bm + row) * 128 + col]);
        *reinterpret_cast<f16x8*>(&As[row][col]) = v;
    }
    __syncthreads();

    f32x4 acc[4] = {f32x4{0,0,0,0}, f32x4{0,0,0,0}, f32x4{0,0,0,0}, f32x4{0,0,0,0}};
    const int arow = wv * 16 + (lane & 15);
    const int kgrp = (lane >> 4) * 8;

    #pragma unroll
    for (int ks = 0; ks < 4; ++ks) {
        f16x8 af = *reinterpret_cast<const f16x8*>(&As[arow][ks * 32 + kgrp]);
        #pragma unroll
        for (int t = 0; t < 4; ++t) {
            int slot = (ks * 4 + t) * 64 + lane;
            f16x8 bf = *reinterpret_cast<const f16x8*>(&w2f[slot * 8]);
            acc[t] = __builtin_amdgcn_mfma_f32_16x16x32_f16(af, bf, acc[t], 0, 0, 0);
        }
    }

    #pragma unroll
    for (int j = 0; j < 4; ++j) {
        int row = bm + wv * 16 + (lane >> 4) * 4 + j;
        if (row < M) {
            float dv = dis[row];
            #pragma unroll
            for (int t = 0; t < 4; ++t) {
                int col = t * 16 + (lane & 15);
                h2[(size_t)row * 64 + col] = __float2half(acc[t][j] * dv);
            }
        }
    }
}

// -------- agg2 + BN/ReLU + GEMM3 (64->2 wave reduce) -> h3' --------
__global__ __launch_bounds__(256)
void agg2_bnrelu_gemm3(const __half* __restrict__ h2, const float* __restrict__ dis,
                       const int* __restrict__ row_start, const int* __restrict__ csr,
                       const float* __restrict__ bns2, const float* __restrict__ bnb2,
                       const float* __restrict__ w3, float* __restrict__ h3, int n) {
    int node = (blockIdx.x * 256 + threadIdx.x) >> 6;
    int lane = threadIdx.x & 63;
    if (node >= n) return;
    int nd = __builtin_amdgcn_readfirstlane(node);
    float di = dis[nd];
    float acc = __half2float(h2[(size_t)nd * 64 + lane]);
    int rs = row_start[nd], re = row_start[nd + 1];
    for (int j = rs; j < re; j += 8) {
        #pragma unroll
        for (int u = 0; u < 8; ++u) {
            int jj = j + u;
            int s = __builtin_amdgcn_readfirstlane(csr[jj < re ? jj : re - 1]);
            float msk = (jj < re) ? 1.f : 0.f;
            acc += msk * __half2float(h2[(size_t)s * 64 + lane]);
        }
    }
    float y = fmaxf(acc * (di * bns2[lane]) + bnb2[lane], 0.f);
    float r0 = y * w3[lane * 2 + 0];
    float r1 = y * w3[lane * 2 + 1];
    #pragma unroll
    for (int off = 32; off > 0; off >>= 1) {
        r0 += __shfl_down(r0, off);
        r1 += __shfl_down(r1, off);
    }
    if (lane == 0) {
        h3[(size_t)nd * 2 + 0] = r0 * di;
        h3[(size_t)nd * 2 + 1] = r1 * di;
    }
}

// -------- agg3 (F=2, thread/node) + b3 -> out --------
__global__ void agg3(const float* __restrict__ h3, const float* __restrict__ dis,
                     const int* __restrict__ row_start, const int* __restrict__ csr,
                     const float* __restrict__ b3, float* __restrict__ out, int n) {
    int i = blockIdx.x * 256 + threadIdx.x;
    if (i >= n) return;
    float di = dis[i];
    const float2* hp = reinterpret_cast<const float2*>(h3);
    float2 hv = hp[i];
    float ax = hv.x, ay = hv.y;
    int rs = row_start[i], re = row_start[i + 1];
    for (int j = rs; j < re; j += 8) {
        #pragma unroll
        for (int u = 0; u < 8; ++u) {
            int jj = j + u;
            int s = csr[jj < re ? jj : re - 1];
            float msk = (jj < re) ? 1.f : 0.f;
            float2 v = hp[s];
            ax += msk * v.x;
            ay += msk * v.y;
        }
    }
    out[(size_t)i * 2 + 0] = ax * di + b3[0];
    out[(size_t)i * 2 + 1] = ay * di + b3[1];
}

// ---------------- launch ----------------

extern "C" void kernel_launch(void* const* d_in, const int* in_sizes, int n_in,
                              void* d_out, int out_size, void* d_ws, size_t ws_size,
                              hipStream_t stream) {
    const float* x   = (const float*)d_in[0];
    const int*   ei  = (const int*)d_in[1];
    const float* w1  = (const float*)d_in[2];
    const float* b1  = (const float*)d_in[3];
    const float* g1  = (const float*)d_in[4];
    const float* bt1 = (const float*)d_in[5];
    const float* m1  = (const float*)d_in[6];
    const float* v1  = (const float*)d_in[7];
    const float* w2  = (const float*)d_in[8];
    const float* b2  = (const float*)d_in[9];
    const float* g2  = (const float*)d_in[10];
    const float* bt2 = (const float*)d_in[11];
    const float* m2  = (const float*)d_in[12];
    const float* v2  = (const float*)d_in[13];
    const float* w3  = (const float*)d_in[14];
    const float* b3  = (const float*)d_in[15];
    float* out = (float*)d_out;

    const int* srcp = ei;        // edge_index[0]
    const int* dstp = ei + NE;   // edge_index[1]

    char* ws = (char*)d_ws;
    int*    cnt       = (int*)(ws + 0);            // 200 KB
    int*    row_start = (int*)(ws + 200064);       // 200 KB
    int*    csr       = (int*)(ws + 400128);       // 3.2 MB
    float*  dis       = (float*)(ws + 3600192);    // 200 KB
    __half* w1f       = (__half*)(ws + 3800256);   // 128 KB (frag-packed)
    __half* w2f       = (__half*)(ws + 3931392);   // 16 KB  (frag-packed)
    float*  bns1      = (float*)(ws + 3947840);
    float*  bnb1      = (float*)(ws + 3948352);
    float*  bns2      = (float*)(ws + 3948864);
    float*  bnb2      = (float*)(ws + 3949120);
    __half* h1        = (__half*)(ws + 4000256);   // 12.8 MB (50000x128 fp16)
    __half* a1        = (__half*)(ws + 16800512);  // 12.8 MB (50000x128 fp16)
    __half* h2        = (__half*)(ws + 29600768);  // 6.4 MB  (50000x64 fp16)
    float*  h3        = (float*)(ws + 36000832);   // 400 KB  (50000x2 fp32)

    hipMemsetAsync(cnt, 0, NN * sizeof(int), stream);

    k_prep<<<(512 * 128 + 128 * 64 + 192 + 255) / 256, 256, 0, stream>>>(
        w1, w2, b1, g1, bt1, m1, v1, b2, g2, bt2, m2, v2,
        w1f, w2f, bns1, bnb1, bns2, bnb2);
    k_count<<<(NE + 255) / 256, 256, 0, stream>>>(dstp, cnt, NE);
    k_scan<<<1, 1024, 0, stream>>>(cnt, row_start, dis, NN);
    k_fill<<<(NE + 255) / 256, 256, 0, stream>>>(srcp, dstp, row_start, cnt, csr, NE);

    // h1' = fp16((x @ w1) * dis)
    gemm1_mfma<<<(NN + 31) / 32, 256, 0, stream>>>(x, w1f, dis, h1, NN);
    // a1 = ReLU(BN(agg(h1')))
    agg1_bn<<<(NN * 64 + 511) / 512, 512, 0, stream>>>(
        h1, dis, row_start, csr, bns1, bnb1, a1, NN);
    // h2' = fp16((a1 @ w2) * dis)
    gemm2_mfma<<<(NN + 63) / 64, 256, 0, stream>>>(a1, w2f, dis, h2, NN);
    // agg2 + BN/ReLU + GEMM3 -> h3'
    agg2_bnrelu_gemm3<<<(NN * 64 + 255) / 256, 256, 0, stream>>>(
        h2, dis, row_start, csr, bns2, bnb2, w3, h3, NN);
    // agg3 + b3 -> out
    agg3<<<(NN + 255) / 256, 256, 0, stream>>>(h3, dis, row_start, csr, b3, out, NN);
}